// Round 6
// baseline (138.368 us; speedup 1.0000x reference)
//
#include <hip/hip_runtime.h>
#include <hip/hip_bf16.h>

#define NTOK 128
#define CHN  512
#define KTOT 1024
#define EPSV 1e-5f

typedef __attribute__((ext_vector_type(8))) short bf16x8;
typedef __attribute__((ext_vector_type(4))) float f32x4;

union BfPack4 { ushort4 u; __hip_bfloat16 h[4]; };

// ws layout (bytes):
//   0     : xT4  fp32 [16][128 c4][128 j][4]  4 MB   (packed 4-channel groups)
//   4 MB  : part fp32 [8 s][16 b][128 i][128 j] 8 MB
//   12 MB : hb   bf16 [2048][1024]            4 MB
//   16 MB : wfb  bf16 [512][1024]             1 MB
//   17 MB : xTbf bf16 [16][512 c][128 j]      2 MB

// ---------------------------------------------------------------------------
// K0: per block (b, jt, ct): 64x64 tile of x -> xT4 (fp32 packed), xTbf (bf16
//     [c][j]), and bf16 x rows into hb-left. 256 blocks x 256 thr.
// ---------------------------------------------------------------------------
__global__ __launch_bounds__(256)
void k0_transpose(const float* __restrict__ xg,
                  float* __restrict__ xT4,
                  __hip_bfloat16* __restrict__ xTbf,
                  __hip_bfloat16* __restrict__ hb)
{
    __shared__ float ts[64 * 68];
    const int t  = threadIdx.x;
    const int bk = blockIdx.x;
    const int b  = bk >> 4;
    const int jt = (bk >> 3) & 1;
    const int ct = bk & 7;
    const int j0 = jt * 64, c0 = ct * 64;

    // load 64 rows x 64 cols; thread: row j0+(t>>2), 16 floats at quad*16
    const int jr = t >> 2, qd = t & 3;
    const float* src = xg + ((size_t)(b * NTOK) + j0 + jr) * CHN + c0 + qd * 16;
    float4 v0 = *(const float4*)&src[0];
    float4 v1 = *(const float4*)&src[4];
    float4 v2 = *(const float4*)&src[8];
    float4 v3 = *(const float4*)&src[12];
    *(float4*)&ts[jr * 68 + qd * 16 + 0]  = v0;
    *(float4*)&ts[jr * 68 + qd * 16 + 4]  = v1;
    *(float4*)&ts[jr * 68 + qd * 16 + 8]  = v2;
    *(float4*)&ts[jr * 68 + qd * 16 + 12] = v3;

    // hb-left bf16 from registers
    {
        __hip_bfloat16* hrow = hb + ((size_t)(b * NTOK) + j0 + jr) * KTOT + c0 + qd * 16;
        BfPack4 p;
        p.h[0]=__float2bfloat16(v0.x); p.h[1]=__float2bfloat16(v0.y);
        p.h[2]=__float2bfloat16(v0.z); p.h[3]=__float2bfloat16(v0.w);
        *(ushort4*)&hrow[0] = p.u;
        p.h[0]=__float2bfloat16(v1.x); p.h[1]=__float2bfloat16(v1.y);
        p.h[2]=__float2bfloat16(v1.z); p.h[3]=__float2bfloat16(v1.w);
        *(ushort4*)&hrow[4] = p.u;
        p.h[0]=__float2bfloat16(v2.x); p.h[1]=__float2bfloat16(v2.y);
        p.h[2]=__float2bfloat16(v2.z); p.h[3]=__float2bfloat16(v2.w);
        *(ushort4*)&hrow[8] = p.u;
        p.h[0]=__float2bfloat16(v3.x); p.h[1]=__float2bfloat16(v3.y);
        p.h[2]=__float2bfloat16(v3.z); p.h[3]=__float2bfloat16(v3.w);
        *(ushort4*)&hrow[12] = p.u;
    }
    __syncthreads();

    // write packed transposed: lane jr2 = t&63 owns column j0+jr2; 4 c-groups
    const int jr2 = t & 63;
    #pragma unroll
    for (int m = 0; m < 4; ++m) {
        const int cg = (t >> 6) * 4 + m;            // 0..15 channel-quad within tile
        float4 f4 = *(const float4*)&ts[jr2 * 68 + cg * 4];   // 4 consecutive c, fixed j
        const size_t slot = ((size_t)(b * 128) + (c0 >> 2) + cg) * NTOK + j0 + jr2;
        *(float4*)&xT4[slot * 4] = f4;
        const int c = c0 + cg * 4;
        xTbf[((size_t)(b * CHN) + c + 0) * NTOK + j0 + jr2] = __float2bfloat16(f4.x);
        xTbf[((size_t)(b * CHN) + c + 1) * NTOK + j0 + jr2] = __float2bfloat16(f4.y);
        xTbf[((size_t)(b * CHN) + c + 2) * NTOK + j0 + jr2] = __float2bfloat16(f4.z);
        xTbf[((size_t)(b * CHN) + c + 3) * NTOK + j0 + jr2] = __float2bfloat16(f4.w);
    }
}

// ---------------------------------------------------------------------------
// K1a: partial scores. block = (b, 8-row i-band, 64-ch slice). 2048 blocks x
// 128 thr, no LDS/barriers. lane j: one float4 xj load per 4 channels;
// xi/wd wave-uniform s_loads amortized over 8 i-rows.
// ---------------------------------------------------------------------------
__global__ __launch_bounds__(128)
void k1a_scores(const float* __restrict__ xg,
                const float* __restrict__ xT4,
                const float* __restrict__ wde,
                float* __restrict__ part)
{
    const int bk = blockIdx.x;
    const int s  = bk & 7;
    const int iq = (bk >> 3) & 15;
    const int b  = bk >> 7;
    const int i0 = iq * 8;
    const int c0 = s * 64;
    const int j  = threadIdx.x;

    const float* xt  = xT4 + ((size_t)(b * 128 + s * 16) * NTOK + j) * 4;
    const float* xip = xg + ((size_t)(b * NTOK) + i0) * CHN + c0;

    float acc[8];
    #pragma unroll
    for (int r = 0; r < 8; ++r) acc[r] = 0.f;

    #pragma unroll 4
    for (int g = 0; g < 16; ++g) {
        const float4 xj = *(const float4*)(xt + (size_t)g * NTOK * 4);
        const float4 wd = *(const float4*)&wde[c0 + g * 4];          // uniform
        #pragma unroll
        for (int r = 0; r < 8; ++r) {
            const float4 xi = *(const float4*)&xip[r * CHN + g * 4]; // uniform
            acc[r] += fabsf(xi.x - xj.x) * wd.x + fabsf(xi.y - xj.y) * wd.y
                    + fabsf(xi.z - xj.z) * wd.z + fabsf(xi.w - xj.w) * wd.w;
        }
    }

    float* pp = part + ((size_t)(s * 16 + b)) * (NTOK * NTOK) + (size_t)i0 * NTOK + j;
    #pragma unroll
    for (int r = 0; r < 8; ++r) pp[r * NTOK] = acc[r];
}

// ---------------------------------------------------------------------------
// K1bc: fused softmax + xnb GEMM (+ Wf->bf16). 512 blocks x 256 thr.
// block = (b, 32-row i-tile, 64-col c-tile). Softmax for the 32 rows is
// recomputed per c-tile (8x redundancy, all L2); W -> LDS -> MFMA A-frag.
// ---------------------------------------------------------------------------
__global__ __launch_bounds__(256)
void k1bc_softmax_xnb(const float* __restrict__ part,
                      const float* __restrict__ bn_e_g,
                      const float* __restrict__ bn_e_v,
                      const __hip_bfloat16* __restrict__ xTbf,
                      const float* __restrict__ wf,
                      __hip_bfloat16* __restrict__ hb,
                      __hip_bfloat16* __restrict__ wfb)
{
    __shared__ unsigned short WL[32 * 128];    // W rows (bf16), 8 KB
    const int bk = blockIdx.x;
    const int t  = threadIdx.x;

    // Wf row bk -> bf16 (independent)
    {
        const float* wr = wf + (size_t)bk * KTOT;
        float4 u = *(const float4*)&wr[t * 4];
        BfPack4 p;
        p.h[0]=__float2bfloat16(u.x); p.h[1]=__float2bfloat16(u.y);
        p.h[2]=__float2bfloat16(u.z); p.h[3]=__float2bfloat16(u.w);
        *(ushort4*)&wfb[(size_t)bk * KTOT + t * 4] = p.u;
    }

    const int b  = bk >> 5;
    const int mt = (bk >> 3) & 3;
    const int ct = bk & 7;
    const int i0 = mt * 32, c0 = ct * 64;

    // ---- softmax: thread t owns row r = t>>3, j-segment (t&7)*16 ----
    {
        const int r    = t >> 3;
        const int jseg = (t & 7) * 16;
        const int gi   = i0 + r;                 // global row within batch

        float4 s0 = {0,0,0,0}, s1 = s0, s2 = s0, s3 = s0;
        #pragma unroll
        for (int s = 0; s < 8; ++s) {
            const float* pp = part + ((size_t)(s * 16 + b)) * (NTOK * NTOK)
                            + (size_t)gi * NTOK + jseg;
            float4 a = *(const float4*)&pp[0];
            float4 bq = *(const float4*)&pp[4];
            float4 cq = *(const float4*)&pp[8];
            float4 dq = *(const float4*)&pp[12];
            s0.x+=a.x; s0.y+=a.y; s0.z+=a.z; s0.w+=a.w;
            s1.x+=bq.x; s1.y+=bq.y; s1.z+=bq.z; s1.w+=bq.w;
            s2.x+=cq.x; s2.y+=cq.y; s2.z+=cq.z; s2.w+=cq.w;
            s3.x+=dq.x; s3.y+=dq.y; s3.z+=dq.z; s3.w+=dq.w;
        }
        const float sc = bn_e_g[0] * rsqrtf(bn_e_v[0] + EPSV);
        float l[16] = { s0.x,s0.y,s0.z,s0.w, s1.x,s1.y,s1.z,s1.w,
                        s2.x,s2.y,s2.z,s2.w, s3.x,s3.y,s3.z,s3.w };
        #pragma unroll
        for (int k = 0; k < 16; ++k) l[k] *= sc;
        if (gi >= jseg && gi < jseg + 16) l[gi - jseg] -= 1e8f;   // diagonal

        float m = l[0];
        #pragma unroll
        for (int k = 1; k < 16; ++k) m = fmaxf(m, l[k]);
        m = fmaxf(m, __shfl_xor(m, 1));
        m = fmaxf(m, __shfl_xor(m, 2));
        m = fmaxf(m, __shfl_xor(m, 4));
        float e[16], ssum = 0.f;
        #pragma unroll
        for (int k = 0; k < 16; ++k) { e[k] = __expf(l[k] - m); ssum += e[k]; }
        ssum += __shfl_xor(ssum, 1);
        ssum += __shfl_xor(ssum, 2);
        ssum += __shfl_xor(ssum, 4);
        const float inv = 1.f / ssum;
        #pragma unroll
        for (int k4 = 0; k4 < 4; ++k4) {
            BfPack4 p;
            p.h[0] = __float2bfloat16(e[k4*4+0] * inv);
            p.h[1] = __float2bfloat16(e[k4*4+1] * inv);
            p.h[2] = __float2bfloat16(e[k4*4+2] * inv);
            p.h[3] = __float2bfloat16(e[k4*4+3] * inv);
            *(ushort4*)&WL[r * 128 + jseg + k4 * 4] = p.u;
        }
    }
    __syncthreads();

    // ---- MFMA: xnb tile (32 i x 64 c), K = 128 (j). A from LDS, B global. ----
    const int w    = t >> 6;
    const int lane = t & 63;
    const int wm   = w & 1;
    const int wn   = w >> 1;
    const int m16  = lane & 15;
    const int q    = lane >> 4;

    const unsigned short* A0 = &WL[(wm * 16 + m16) * 128 + q * 8];
    const short* B0 = (const short*)xTbf + ((size_t)(b * CHN) + c0 + wn * 32 + m16) * NTOK + q * 8;

    f32x4 acc0 = {0.f, 0.f, 0.f, 0.f};
    f32x4 acc1 = acc0;

    #pragma unroll
    for (int k0 = 0; k0 < NTOK; k0 += 32) {
        const bf16x8 a  = *(const bf16x8*)(A0 + k0);
        const bf16x8 b0 = *(const bf16x8*)(B0 + k0);
        const bf16x8 b1 = *(const bf16x8*)(B0 + 16 * NTOK + k0);
        acc0 = __builtin_amdgcn_mfma_f32_16x16x32_bf16(a, b0, acc0, 0, 0, 0);
        acc1 = __builtin_amdgcn_mfma_f32_16x16x32_bf16(a, b1, acc1, 0, 0, 0);
    }

    // D layout: col = lane&15 (-> c), row = q*4+r (-> i)
    #pragma unroll
    for (int ni = 0; ni < 2; ++ni) {
        const int c = c0 + wn * 32 + ni * 16 + m16;
        const f32x4 ac = ni ? acc1 : acc0;
        #pragma unroll
        for (int r = 0; r < 4; ++r) {
            const int i = i0 + wm * 16 + q * 4 + r;
            hb[(size_t)(b * NTOK + i) * KTOT + CHN + c] = __float2bfloat16(ac[r]);
        }
    }
}

// ---------------------------------------------------------------------------
// K2: out = relu(BN([x|xnb] @ Wf^T + bias)) via bf16 MFMA. UNCHANGED (control).
// ---------------------------------------------------------------------------
__global__ __launch_bounds__(256)
void k2_gemm_bn_relu(const __hip_bfloat16* __restrict__ hbp,
                     const __hip_bfloat16* __restrict__ wfbp,
                     const float* __restrict__ fb,
                     const float* __restrict__ gg,
                     const float* __restrict__ bb,
                     const float* __restrict__ mm,
                     const float* __restrict__ vv,
                     float* __restrict__ out)
{
    const int blk  = blockIdx.x;
    const int r0   = (blk >> 3) << 6;
    const int c0   = (blk & 7) << 6;
    const int t    = threadIdx.x;
    const int w    = t >> 6;
    const int lane = t & 63;
    const int wm   = w & 1;
    const int wn   = w >> 1;
    const int m16  = lane & 15;
    const int qq   = lane >> 4;

    const short* A0 = (const short*)hbp  + (size_t)(r0 + wm * 32 + m16) * KTOT + qq * 8;
    const short* B0 = (const short*)wfbp + (size_t)(c0 + wn * 32 + m16) * KTOT + qq * 8;

    f32x4 acc00 = {0.f, 0.f, 0.f, 0.f};
    f32x4 acc01 = acc00, acc10 = acc00, acc11 = acc00;

    #pragma unroll 4
    for (int k0 = 0; k0 < KTOT; k0 += 32) {
        const bf16x8 aA = *(const bf16x8*)(A0 + k0);
        const bf16x8 aB = *(const bf16x8*)(A0 + 16 * KTOT + k0);
        const bf16x8 bA = *(const bf16x8*)(B0 + k0);
        const bf16x8 bB = *(const bf16x8*)(B0 + 16 * KTOT + k0);
        acc00 = __builtin_amdgcn_mfma_f32_16x16x32_bf16(aA, bA, acc00, 0, 0, 0);
        acc01 = __builtin_amdgcn_mfma_f32_16x16x32_bf16(aA, bB, acc01, 0, 0, 0);
        acc10 = __builtin_amdgcn_mfma_f32_16x16x32_bf16(aB, bA, acc10, 0, 0, 0);
        acc11 = __builtin_amdgcn_mfma_f32_16x16x32_bf16(aB, bB, acc11, 0, 0, 0);
    }

    #pragma unroll
    for (int ni = 0; ni < 2; ++ni) {
        const int c = c0 + wn * 32 + ni * 16 + m16;
        const float gf = gg[c] * rsqrtf(vv[c] + EPSV);
        const float ad = fb[c] - mm[c];
        const float bv = bb[c];
        const f32x4 acr0 = ni ? acc01 : acc00;
        const f32x4 acr1 = ni ? acc11 : acc10;
        #pragma unroll
        for (int r2 = 0; r2 < 4; ++r2) {
            int row = r0 + wm * 32 + qq * 4 + r2;
            float val = (acr0[r2] + ad) * gf + bv;
            out[(size_t)row * CHN + c] = fmaxf(val, 0.f);
            row += 16;
            val = (acr1[r2] + ad) * gf + bv;
            out[(size_t)row * CHN + c] = fmaxf(val, 0.f);
        }
    }
}

extern "C" void kernel_launch(void* const* d_in, const int* in_sizes, int n_in,
                              void* d_out, int out_size, void* d_ws, size_t ws_size,
                              hipStream_t stream) {
    const float* x        = (const float*)d_in[0];
    // d_in[1] = y          : unused (softmax shift-invariance)
    const float* conv_e_w = (const float*)d_in[2];
    // d_in[3] = conv_e_b   : unused (shift)
    const float* bn_e_g   = (const float*)d_in[4];
    // d_in[5,6] bn_e_b, bn_e_m : unused (shift)
    const float* bn_e_v   = (const float*)d_in[7];
    const float* conv_f_w = (const float*)d_in[8];
    const float* conv_f_b = (const float*)d_in[9];
    const float* bn_f_g   = (const float*)d_in[10];
    const float* bn_f_b   = (const float*)d_in[11];
    const float* bn_f_m   = (const float*)d_in[12];
    const float* bn_f_v   = (const float*)d_in[13];
    float* out = (float*)d_out;

    char* ws = (char*)d_ws;
    float*           xT4  = (float*)(ws);                         // 4 MB
    float*           part = (float*)(ws + (4u  << 20));           // 8 MB
    __hip_bfloat16*  hb   = (__hip_bfloat16*)(ws + (12u << 20));  // 4 MB
    __hip_bfloat16*  wfb  = (__hip_bfloat16*)(ws + (16u << 20));  // 1 MB
    __hip_bfloat16*  xTbf = (__hip_bfloat16*)(ws + (17u << 20));  // 2 MB

    k0_transpose<<<256, 256, 0, stream>>>(x, xT4, xTbf, hb);
    k1a_scores<<<2048, 128, 0, stream>>>(x, xT4, conv_e_w, part);
    k1bc_softmax_xnb<<<512, 256, 0, stream>>>(part, bn_e_g, bn_e_v, xTbf,
                                              conv_f_w, hb, wfb);
    k2_gemm_bn_relu<<<256, 256, 0, stream>>>(hb, wfb, conv_f_b, bn_f_g, bn_f_b,
                                             bn_f_m, bn_f_v, out);
}

// Round 7
// 122.772 us; speedup vs baseline: 1.1270x; 1.1270x over previous
//
#include <hip/hip_runtime.h>
#include <hip/hip_bf16.h>

#define NTOK 128
#define CHN  512
#define KTOT 1024
#define EPSV 1e-5f

typedef __attribute__((ext_vector_type(8))) short bf16x8;
typedef __attribute__((ext_vector_type(4))) float f32x4;

union BfPack4 { ushort4 u; __hip_bfloat16 h[4]; };

// ws layout (bytes):
//   0        : xT   fp32 [16][512][128]   4 MB
//   4  MB    : part fp32 [8][16][128][128] 8 MB
//   12 MB    : hb   bf16 [2048][1024]     4 MB
//   16 MB    : wfb  bf16 [512][1024]      1 MB
//   17 MB    : Wbf  bf16 [16][128][128]   512 KB
//   17.5 MB  : xTbf bf16 [16][512][128]   2 MB

// ---------------------------------------------------------------------------
// K0: per block (b, jt, ct): transpose a 64x64 tile of x into xT (fp32+bf16)
//     and emit bf16 x rows into hb-left. 256 blocks x 256 thr.
// ---------------------------------------------------------------------------
__global__ __launch_bounds__(256)
void k0_transpose(const float* __restrict__ xg,
                  float* __restrict__ xT,
                  __hip_bfloat16* __restrict__ xTbf,
                  __hip_bfloat16* __restrict__ hb)
{
    __shared__ float ts[64 * 68];   // pad 68: rows 16B-aligned
    const int t  = threadIdx.x;
    const int bk = blockIdx.x;
    const int b  = bk >> 4;
    const int jt = (bk >> 3) & 1;
    const int ct = bk & 7;
    const int j0 = jt * 64, c0 = ct * 64;

    // load 64 rows x 64 cols; thread: row j0+(t>>2), 16 floats at quad*16
    const int jr = t >> 2, qd = t & 3;
    const float* src = xg + ((size_t)(b * NTOK) + j0 + jr) * CHN + c0 + qd * 16;
    float4 v0 = *(const float4*)&src[0];
    float4 v1 = *(const float4*)&src[4];
    float4 v2 = *(const float4*)&src[8];
    float4 v3 = *(const float4*)&src[12];
    *(float4*)&ts[jr * 68 + qd * 16 + 0]  = v0;
    *(float4*)&ts[jr * 68 + qd * 16 + 4]  = v1;
    *(float4*)&ts[jr * 68 + qd * 16 + 8]  = v2;
    *(float4*)&ts[jr * 68 + qd * 16 + 12] = v3;

    // hb-left bf16 from registers (row b*128+j0+jr, cols c0+qd*16..+16)
    {
        __hip_bfloat16* hrow = hb + ((size_t)(b * NTOK) + j0 + jr) * KTOT + c0 + qd * 16;
        BfPack4 p;
        p.h[0]=__float2bfloat16(v0.x); p.h[1]=__float2bfloat16(v0.y);
        p.h[2]=__float2bfloat16(v0.z); p.h[3]=__float2bfloat16(v0.w);
        *(ushort4*)&hrow[0] = p.u;
        p.h[0]=__float2bfloat16(v1.x); p.h[1]=__float2bfloat16(v1.y);
        p.h[2]=__float2bfloat16(v1.z); p.h[3]=__float2bfloat16(v1.w);
        *(ushort4*)&hrow[4] = p.u;
        p.h[0]=__float2bfloat16(v2.x); p.h[1]=__float2bfloat16(v2.y);
        p.h[2]=__float2bfloat16(v2.z); p.h[3]=__float2bfloat16(v2.w);
        *(ushort4*)&hrow[8] = p.u;
        p.h[0]=__float2bfloat16(v3.x); p.h[1]=__float2bfloat16(v3.y);
        p.h[2]=__float2bfloat16(v3.z); p.h[3]=__float2bfloat16(v3.w);
        *(ushort4*)&hrow[12] = p.u;
    }
    __syncthreads();

    // write transposed: thread: cs = t>>4 (c = cs+16m), jj = (t&15)*4
    const int cs = t >> 4, jj = (t & 15) * 4;
    #pragma unroll
    for (int m = 0; m < 4; ++m) {
        const int c = cs + 16 * m;
        float4 o;
        o.x = ts[(jj + 0) * 68 + c];
        o.y = ts[(jj + 1) * 68 + c];
        o.z = ts[(jj + 2) * 68 + c];
        o.w = ts[(jj + 3) * 68 + c];
        const size_t base = ((size_t)(b * CHN) + c0 + c) * NTOK + j0 + jj;
        *(float4*)&xT[base] = o;
        BfPack4 p;
        p.h[0]=__float2bfloat16(o.x); p.h[1]=__float2bfloat16(o.y);
        p.h[2]=__float2bfloat16(o.z); p.h[3]=__float2bfloat16(o.w);
        *(ushort4*)&xTbf[base] = p.u;
    }
}

// ---------------------------------------------------------------------------
// K1a: partial scores. block = (b, i-quad, ch-slice of 64). 4096 blocks x 128
// thr, NO LDS, NO barriers. lane j reads xT coalesced; xi/wd wave-uniform.
// part[s][b][i][j] += sum_{c in slice} |x_i,c - x_j,c| * wd_c
// ---------------------------------------------------------------------------
__global__ __launch_bounds__(128)
void k1a_scores(const float* __restrict__ xg,
                const float* __restrict__ xT,
                const float* __restrict__ wde,
                float* __restrict__ part)
{
    const int bk = blockIdx.x;
    const int s  = bk & 7;
    const int iq = (bk >> 3) & 31;
    const int b  = bk >> 8;
    const int i0 = iq * 4;
    const int c0 = s * 64;
    const int j  = threadIdx.x;

    const float* xtp = xT + ((size_t)(b * CHN) + c0) * NTOK + j;
    const float* xip = xg + ((size_t)(b * NTOK) + i0) * CHN + c0;

    float acc0 = 0.f, acc1 = 0.f, acc2 = 0.f, acc3 = 0.f;

    #pragma unroll 2
    for (int cc = 0; cc < 64; cc += 8) {
        float xj[8];
        #pragma unroll
        for (int k = 0; k < 8; ++k) xj[k] = xtp[(cc + k) * NTOK];
        #pragma unroll
        for (int k = 0; k < 8; ++k) {
            const int c = cc + k;
            const float wd  = wde[c0 + c];          // uniform -> SGPR
            const float xi0 = xip[0 * CHN + c];     // uniform -> SGPR
            const float xi1 = xip[1 * CHN + c];
            const float xi2 = xip[2 * CHN + c];
            const float xi3 = xip[3 * CHN + c];
            acc0 += fabsf(xi0 - xj[k]) * wd;
            acc1 += fabsf(xi1 - xj[k]) * wd;
            acc2 += fabsf(xi2 - xj[k]) * wd;
            acc3 += fabsf(xi3 - xj[k]) * wd;
        }
    }

    float* pp = part + ((size_t)s * 16 + b) * (NTOK * NTOK) + (size_t)i0 * NTOK + j;
    pp[0 * NTOK] = acc0;
    pp[1 * NTOK] = acc1;
    pp[2 * NTOK] = acc2;
    pp[3 * NTOK] = acc3;
}

// ---------------------------------------------------------------------------
// K1b: softmax per row. 1024 blocks x 128 thr; wave w owns row i0+w.
// lane l handles j=l and j=l+64. Butterfly-only, no LDS, no barriers.
// ---------------------------------------------------------------------------
__global__ __launch_bounds__(128)
void k1b_softmax(const float* __restrict__ part,
                 const float* __restrict__ bn_e_g,
                 const float* __restrict__ bn_e_v,
                 __hip_bfloat16* __restrict__ Wbf)
{
    const int bk = blockIdx.x;
    const int b  = bk >> 6;
    const int i  = (bk & 63) * 2 + (threadIdx.x >> 6);
    const int l  = threadIdx.x & 63;

    const float* pp = part + (size_t)(b * NTOK + i) * NTOK;
    float p1 = 0.f, p2 = 0.f;
    #pragma unroll
    for (int s = 0; s < 8; ++s) {
        p1 += pp[(size_t)s * 16 * NTOK * NTOK + l];
        p2 += pp[(size_t)s * 16 * NTOK * NTOK + l + 64];
    }
    const float sc = bn_e_g[0] * rsqrtf(bn_e_v[0] + EPSV);
    float l1 = p1 * sc - (l == i ? 1e8f : 0.f);
    float l2 = p2 * sc - (l + 64 == i ? 1e8f : 0.f);

    float m = fmaxf(l1, l2);
    #pragma unroll
    for (int off = 32; off > 0; off >>= 1) m = fmaxf(m, __shfl_xor(m, off));
    const float e1 = __expf(l1 - m);
    const float e2 = __expf(l2 - m);
    float ssum = e1 + e2;
    #pragma unroll
    for (int off = 32; off > 0; off >>= 1) ssum += __shfl_xor(ssum, off);
    const float inv = 1.f / ssum;

    __hip_bfloat16* wr = Wbf + (size_t)(b * NTOK + i) * NTOK;
    wr[l]      = __float2bfloat16(e1 * inv);
    wr[l + 64] = __float2bfloat16(e2 * inv);
}

// ---------------------------------------------------------------------------
// K1c: xnb = W @ x via bf16 MFMA -> hb right half; also converts Wf -> bf16.
// 512 blocks x 256 thr. Block: (b, i-tile 32, c-tile 64), K = 128 (j).
// ---------------------------------------------------------------------------
__global__ __launch_bounds__(256)
void k1c_xnb(const __hip_bfloat16* __restrict__ Wbf,
             const __hip_bfloat16* __restrict__ xTbf,
             const float* __restrict__ wf,
             __hip_bfloat16* __restrict__ hb,
             __hip_bfloat16* __restrict__ wfb)
{
    const int bk = blockIdx.x;
    const int t  = threadIdx.x;

    // Wf row bk -> bf16 (independent of the GEMM below)
    {
        const float* wr = wf + (size_t)bk * KTOT;
        float4 u = *(const float4*)&wr[t * 4];
        BfPack4 p;
        p.h[0]=__float2bfloat16(u.x); p.h[1]=__float2bfloat16(u.y);
        p.h[2]=__float2bfloat16(u.z); p.h[3]=__float2bfloat16(u.w);
        *(ushort4*)&wfb[(size_t)bk * KTOT + t * 4] = p.u;
    }

    const int b  = bk >> 5;
    const int mt = (bk >> 3) & 3;     // i-tile of 32
    const int ct = bk & 7;            // c-tile of 64
    const int i0 = mt * 32, c0 = ct * 64;

    const int w    = t >> 6;
    const int lane = t & 63;
    const int wm   = w & 1;           // 16-row half
    const int wn   = w >> 1;          // 32-col half
    const int m16  = lane & 15;
    const int q    = lane >> 4;

    const short* A0 = (const short*)Wbf  + (size_t)(b * NTOK + i0 + wm * 16 + m16) * NTOK + q * 8;
    const short* B0 = (const short*)xTbf + ((size_t)(b * CHN) + c0 + wn * 32 + m16) * NTOK + q * 8;

    f32x4 acc0 = {0.f, 0.f, 0.f, 0.f};
    f32x4 acc1 = acc0;

    #pragma unroll
    for (int k0 = 0; k0 < NTOK; k0 += 32) {
        const bf16x8 a  = *(const bf16x8*)(A0 + k0);
        const bf16x8 b0 = *(const bf16x8*)(B0 + k0);
        const bf16x8 b1 = *(const bf16x8*)(B0 + 16 * NTOK + k0);
        acc0 = __builtin_amdgcn_mfma_f32_16x16x32_bf16(a, b0, acc0, 0, 0, 0);
        acc1 = __builtin_amdgcn_mfma_f32_16x16x32_bf16(a, b1, acc1, 0, 0, 0);
    }

    // D layout: col = lane&15 (-> c), row = q*4+r (-> i)  [verified pattern]
    #pragma unroll
    for (int ni = 0; ni < 2; ++ni) {
        const int c = c0 + wn * 32 + ni * 16 + m16;
        const f32x4 ac = ni ? acc1 : acc0;
        #pragma unroll
        for (int r = 0; r < 4; ++r) {
            const int i = i0 + wm * 16 + q * 4 + r;
            hb[(size_t)(b * NTOK + i) * KTOT + CHN + c] = __float2bfloat16(ac[r]);
        }
    }
}

// ---------------------------------------------------------------------------
// K2: out = relu(BN([x|xnb] @ Wf^T + bias)) via bf16 MFMA. UNCHANGED (control).
// ---------------------------------------------------------------------------
__global__ __launch_bounds__(256)
void k2_gemm_bn_relu(const __hip_bfloat16* __restrict__ hbp,
                     const __hip_bfloat16* __restrict__ wfbp,
                     const float* __restrict__ fb,
                     const float* __restrict__ gg,
                     const float* __restrict__ bb,
                     const float* __restrict__ mm,
                     const float* __restrict__ vv,
                     float* __restrict__ out)
{
    const int blk  = blockIdx.x;
    const int r0   = (blk >> 3) << 6;
    const int c0   = (blk & 7) << 6;
    const int t    = threadIdx.x;
    const int w    = t >> 6;
    const int lane = t & 63;
    const int wm   = w & 1;
    const int wn   = w >> 1;
    const int m16  = lane & 15;
    const int qq   = lane >> 4;

    const short* A0 = (const short*)hbp  + (size_t)(r0 + wm * 32 + m16) * KTOT + qq * 8;
    const short* B0 = (const short*)wfbp + (size_t)(c0 + wn * 32 + m16) * KTOT + qq * 8;

    f32x4 acc00 = {0.f, 0.f, 0.f, 0.f};
    f32x4 acc01 = acc00, acc10 = acc00, acc11 = acc00;

    #pragma unroll 4
    for (int k0 = 0; k0 < KTOT; k0 += 32) {
        const bf16x8 aA = *(const bf16x8*)(A0 + k0);
        const bf16x8 aB = *(const bf16x8*)(A0 + 16 * KTOT + k0);
        const bf16x8 bA = *(const bf16x8*)(B0 + k0);
        const bf16x8 bB = *(const bf16x8*)(B0 + 16 * KTOT + k0);
        acc00 = __builtin_amdgcn_mfma_f32_16x16x32_bf16(aA, bA, acc00, 0, 0, 0);
        acc01 = __builtin_amdgcn_mfma_f32_16x16x32_bf16(aA, bB, acc01, 0, 0, 0);
        acc10 = __builtin_amdgcn_mfma_f32_16x16x32_bf16(aB, bA, acc10, 0, 0, 0);
        acc11 = __builtin_amdgcn_mfma_f32_16x16x32_bf16(aB, bB, acc11, 0, 0, 0);
    }

    #pragma unroll
    for (int ni = 0; ni < 2; ++ni) {
        const int c = c0 + wn * 32 + ni * 16 + m16;
        const float gf = gg[c] * rsqrtf(vv[c] + EPSV);
        const float ad = fb[c] - mm[c];
        const float bv = bb[c];
        const f32x4 acr0 = ni ? acc01 : acc00;
        const f32x4 acr1 = ni ? acc11 : acc10;
        #pragma unroll
        for (int r2 = 0; r2 < 4; ++r2) {
            int row = r0 + wm * 32 + qq * 4 + r2;
            float val = (acr0[r2] + ad) * gf + bv;
            out[(size_t)row * CHN + c] = fmaxf(val, 0.f);
            row += 16;
            val = (acr1[r2] + ad) * gf + bv;
            out[(size_t)row * CHN + c] = fmaxf(val, 0.f);
        }
    }
}

extern "C" void kernel_launch(void* const* d_in, const int* in_sizes, int n_in,
                              void* d_out, int out_size, void* d_ws, size_t ws_size,
                              hipStream_t stream) {
    const float* x        = (const float*)d_in[0];
    // d_in[1] = y          : unused (softmax shift-invariance)
    const float* conv_e_w = (const float*)d_in[2];
    // d_in[3] = conv_e_b   : unused (shift)
    const float* bn_e_g   = (const float*)d_in[4];
    // d_in[5,6] bn_e_b, bn_e_m : unused (shift)
    const float* bn_e_v   = (const float*)d_in[7];
    const float* conv_f_w = (const float*)d_in[8];
    const float* conv_f_b = (const float*)d_in[9];
    const float* bn_f_g   = (const float*)d_in[10];
    const float* bn_f_b   = (const float*)d_in[11];
    const float* bn_f_m   = (const float*)d_in[12];
    const float* bn_f_v   = (const float*)d_in[13];
    float* out = (float*)d_out;

    char* ws = (char*)d_ws;
    float*           xT   = (float*)(ws);                               // 4 MB
    float*           part = (float*)(ws + (4u << 20));                  // 8 MB
    __hip_bfloat16*  hb   = (__hip_bfloat16*)(ws + (12u << 20));        // 4 MB
    __hip_bfloat16*  wfb  = (__hip_bfloat16*)(ws + (16u << 20));        // 1 MB
    __hip_bfloat16*  Wbf  = (__hip_bfloat16*)(ws + (17u << 20));        // 512 KB
    __hip_bfloat16*  xTbf = (__hip_bfloat16*)(ws + (17u << 20) + (512u << 10)); // 2 MB

    k0_transpose<<<256, 256, 0, stream>>>(x, xT, xTbf, hb);
    k1a_scores<<<4096, 128, 0, stream>>>(x, xT, conv_e_w, part);
    k1b_softmax<<<1024, 128, 0, stream>>>(part, bn_e_g, bn_e_v, Wbf);
    k1c_xnb<<<512, 256, 0, stream>>>(Wbf, xTbf, conv_f_w, hb, wfb);
    k2_gemm_bn_relu<<<256, 256, 0, stream>>>(hb, wfb, conv_f_b, bn_f_g, bn_f_b,
                                             bn_f_m, bn_f_v, out);
}